// Round 18
// baseline (1329.514 us; speedup 1.0000x reference)
//
#include <hip/hip_runtime.h>
#include <hip/hip_bf16.h>

#define BB 16
#define NPTS 1024
#define KNB 20
#define HC 512

typedef __attribute__((ext_vector_type(8))) short short8;
typedef __attribute__((ext_vector_type(4))) float f32x4;

__device__ __forceinline__ float XV(const float* __restrict__ X, int b, int n, int c)
{
    return X[((size_t)b * NPTS + n) * 3 + c];
}

__device__ __forceinline__ unsigned long long dist2key(float d, int m)
{
    unsigned u = __float_as_uint(d);
    u = (u & 0x80000000u) ? ~u : (u | 0x80000000u);
    return ((unsigned long long)u << 32) | (unsigned)(1023 - m);
}

__device__ __forceinline__ void wave_topk_write(unsigned long long* key,
                                                int* __restrict__ idxo,
                                                size_t obase, int lane)
{
    for (int it = 0; it < KNB; ++it) {
        unsigned long long best = 0ull; int bj = -1;
#pragma unroll
        for (int j = 0; j < 16; ++j) if (key[j] > best) { best = key[j]; bj = j; }
        unsigned long long wbest = best;
        for (int off = 32; off > 0; off >>= 1) {
            const unsigned long long o = __shfl_down(wbest, off, 64);
            if (o > wbest) wbest = o;
        }
        wbest = __shfl(wbest, 0, 64);
        if (best == wbest && bj >= 0) key[bj] = 0ull;
        if (lane == 0) idxo[obase + it] = 1023 - (int)(wbest & 0xFFFFFFFFull);
    }
}

// round-to-nearest-even fp32 -> bf16 bits
__device__ __forceinline__ unsigned short f2bf(float x)
{
    unsigned u = __float_as_uint(x);
    u += 0x7FFFu + ((u >> 16) & 1u);
    return (unsigned short)(u >> 16);
}
__device__ __forceinline__ float bf2f(unsigned short h)
{
    return __uint_as_float(((unsigned)h) << 16);
}

__global__ void sentinel_kernel(float* __restrict__ out, float val)
{
    const int i = blockIdx.x * 256 + threadIdx.x;
    if (i < BB * 40) out[i] = val;
}

// ---------------- fp32 -> (bf16 hi, bf16 lo) split conversion ----------------
__global__ void cvt_kernel(const float* __restrict__ src, unsigned short* __restrict__ hi,
                           unsigned short* __restrict__ lo, int n4)
{
    const int i = blockIdx.x * 256 + threadIdx.x;
    if (i >= n4) return;
    const float4 v = ((const float4*)src)[i];
    const float xs[4] = {v.x, v.y, v.z, v.w};
    ushort4 h, l;
    unsigned short* hp = (unsigned short*)&h;
    unsigned short* lp = (unsigned short*)&l;
#pragma unroll
    for (int j = 0; j < 4; ++j) {
        const unsigned short hb = f2bf(xs[j]);
        hp[j] = hb;
        lp[j] = f2bf(xs[j] - bf2f(hb));
    }
    ((ushort4*)hi)[i] = h;
    ((ushort4*)lo)[i] = l;
}

// ---------------- squared norms ----------------
__global__ void xx_kernel(const float* __restrict__ H, const float* __restrict__ X,
                          float* __restrict__ xx, int cin, int off_in, int use_x)
{
    const int p = blockIdx.x * blockDim.x + threadIdx.x;
    if (p >= BB * NPTS) return;
    float s = 0.f;
    if (use_x) {
        const int b = p >> 10, n = p & 1023;
        for (int c = 0; c < 3; ++c) { const float v = XV(X, b, n, c); s += v * v; }
    } else {
        const float4* r4 = (const float4*)(H + (size_t)p * HC + off_in);
        for (int c4 = 0; c4 < cin / 4; ++c4) {
            const float4 v = r4[c4];
            s += v.x*v.x + v.y*v.y + v.z*v.z + v.w*v.w;
        }
    }
    xx[p] = s;
}

// ---------------- knn, 8 queries per block (CIN=64) ----------------
__global__ __launch_bounds__(256, 3) void knn8_kernel(
    const float* __restrict__ H, const float* __restrict__ xx,
    int* __restrict__ idxo, int off_in)
{
    constexpr int CIN = 64;
    __shared__ __align__(16) float qv[8][CIN];
    __shared__ float dist[8][NPTS];
    __shared__ float sxxq[8];
    const int blk = blockIdx.x;
    const int q0g = blk * 8;
    const int b = q0g >> 10, q0 = q0g & 1023;
    const int tid = threadIdx.x;
    const int base = b * NPTS;

    for (int t = tid; t < 8 * CIN; t += 256) {
        const int q = t >> 6, c = t & 63;
        qv[q][c] = H[(size_t)(base + q0 + q) * HC + off_in + c];
    }
    if (tid < 8) sxxq[tid] = xx[base + q0 + tid];
    __syncthreads();

    const int g = tid >> 3, l = tid & 7;
    float4 aq[8][2];
#pragma unroll
    for (int q = 0; q < 8; ++q)
#pragma unroll
        for (int r = 0; r < 2; ++r)
            aq[q][r] = *(const float4*)&qv[q][4 * (l + 8 * r)];

    for (int it = 0; it < 32; ++it) {
        const int m = g + 32 * it;
        float acc[8] = {0.f,0.f,0.f,0.f,0.f,0.f,0.f,0.f};
#pragma unroll
        for (int r = 0; r < 2; ++r) {
            const float4 v = *(const float4*)(H + (size_t)(base + m) * HC + off_in + 4 * (l + 8 * r));
#pragma unroll
            for (int q = 0; q < 8; ++q)
                acc[q] += aq[q][r].x*v.x + aq[q][r].y*v.y + aq[q][r].z*v.z + aq[q][r].w*v.w;
        }
#pragma unroll
        for (int q = 0; q < 8; ++q) {
            acc[q] += __shfl_xor(acc[q], 1, 64);
            acc[q] += __shfl_xor(acc[q], 2, 64);
            acc[q] += __shfl_xor(acc[q], 4, 64);
        }
        if (l == 0) {
            const float xxm = xx[base + m];
#pragma unroll
            for (int q = 0; q < 8; ++q)
                dist[q][m] = (2.f * acc[q] - sxxq[q]) - xxm;
        }
    }
    __syncthreads();

    const int w = tid >> 6, lane = tid & 63;
    for (int qq = w; qq < 8; qq += 4) {
        unsigned long long key[16];
#pragma unroll
        for (int j = 0; j < 16; ++j) {
            const int m = lane + 64 * j;
            key[j] = dist2key(dist[qq][m], m);
        }
        wave_topk_write(key, idxo, (size_t)(base + q0 + qq) * KNB, lane);
    }
}

// ---------------- knn, 4 queries per block (CIN=128) ----------------
template<int CIN>
__global__ __launch_bounds__(256, 3) void knn4_kernel(
    const float* __restrict__ H, const float* __restrict__ xx,
    int* __restrict__ idxo, int off_in)
{
    __shared__ __align__(16) float qv[4][CIN];
    __shared__ float dist[4][NPTS];
    __shared__ float sxxq[4];
    const int blk = blockIdx.x;
    const int q0g = blk * 4;
    const int b = q0g >> 10, q0 = q0g & 1023;
    const int tid = threadIdx.x;
    const int base = b * NPTS;

    for (int t = tid; t < 4 * CIN; t += 256) {
        const int q = t / CIN, c = t - q * CIN;
        qv[q][c] = H[(size_t)(base + q0 + q) * HC + off_in + c];
    }
    if (tid < 4) sxxq[tid] = xx[base + q0 + tid];
    __syncthreads();

    const int g = tid >> 3, l = tid & 7;
    float4 aq[4][CIN / 32];
#pragma unroll
    for (int q = 0; q < 4; ++q)
#pragma unroll
        for (int r = 0; r < CIN / 32; ++r)
            aq[q][r] = *(const float4*)&qv[q][4 * (l + 8 * r)];

    for (int it = 0; it < 32; ++it) {
        const int m = g + 32 * it;
        float acc[4] = {0.f, 0.f, 0.f, 0.f};
#pragma unroll
        for (int r = 0; r < CIN / 32; ++r) {
            const float4 v = *(const float4*)(H + (size_t)(base + m) * HC + off_in + 4 * (l + 8 * r));
#pragma unroll
            for (int q = 0; q < 4; ++q)
                acc[q] += aq[q][r].x*v.x + aq[q][r].y*v.y + aq[q][r].z*v.z + aq[q][r].w*v.w;
        }
#pragma unroll
        for (int q = 0; q < 4; ++q) {
            acc[q] += __shfl_xor(acc[q], 1, 64);
            acc[q] += __shfl_xor(acc[q], 2, 64);
            acc[q] += __shfl_xor(acc[q], 4, 64);
        }
        if (l == 0) {
            const float xxm = xx[base + m];
#pragma unroll
            for (int q = 0; q < 4; ++q)
                dist[q][m] = (2.f * acc[q] - sxxq[q]) - xxm;
        }
    }
    __syncthreads();

    const int w = tid >> 6, lane = tid & 63;
    unsigned long long key[16];
#pragma unroll
    for (int j = 0; j < 16; ++j) {
        const int m = lane + 64 * j;
        key[j] = dist2key(dist[w][m], m);
    }
    wave_topk_write(key, idxo, (size_t)(base + q0 + w) * KNB, lane);
}

// knn over x (cin=3), 4 queries per block
__global__ __launch_bounds__(256, 3) void knn4x_kernel(
    const float* __restrict__ X, const float* __restrict__ xx, int* __restrict__ idxo)
{
    __shared__ float qv[4][4];
    __shared__ float dist[4][NPTS];
    __shared__ float sxxq[4];
    const int blk = blockIdx.x;
    const int q0g = blk * 4;
    const int b = q0g >> 10, q0 = q0g & 1023;
    const int tid = threadIdx.x;
    const int base = b * NPTS;

    if (tid < 4) {
        for (int c = 0; c < 3; ++c) qv[tid][c] = XV(X, b, q0 + tid, c);
        sxxq[tid] = xx[base + q0 + tid];
    }
    __syncthreads();

    for (int j = 0; j < 4; ++j) {
        const int m = tid + 256 * j;
        const float r0 = XV(X, b, m, 0), r1 = XV(X, b, m, 1), r2 = XV(X, b, m, 2);
        const float xxm = xx[base + m];
#pragma unroll
        for (int q = 0; q < 4; ++q) {
            const float acc = qv[q][0]*r0 + qv[q][1]*r1 + qv[q][2]*r2;
            dist[q][m] = (2.f * acc - sxxq[q]) - xxm;
        }
    }
    __syncthreads();

    const int w = tid >> 6, lane = tid & 63;
    unsigned long long key[16];
#pragma unroll
    for (int j = 0; j < 16; ++j) {
        const int m = lane + 64 * j;
        key[j] = dist2key(dist[w][m], m);
    }
    wave_topk_write(key, idxo, (size_t)(base + q0 + w) * KNB, lane);
}

// scalar weight fetch for gemm_conv staging: row og of [W1; W2-W1], column c
__device__ __forceinline__ float wfetch1(const float* __restrict__ W, int og,
                                         int CIN, int COUT, int c)
{
    if (og < COUT) return W[(size_t)og * 2 * CIN + c];
    const float* r0 = W + (size_t)(og - COUT) * 2 * CIN;
    return r0[CIN + c] - r0[c];
}

// ---------------- P GEMM (round-15 proven): 64 rows x 128 cols ----------------
__global__ __launch_bounds__(256, 4) void gemm_conv_kernel(
    const float* __restrict__ H, const float* __restrict__ W, float* __restrict__ P,
    int off_in, int CIN, int COUT, int NO128)
{
    __shared__ float hl[32][68];
    __shared__ float wl[32][133];
    const int mblk = blockIdx.x / NO128;
    const int oblk = blockIdx.x - mblk * NO128;
    const int tid = threadIdx.x;
    const int o = tid & 63, grp = tid >> 6;
    const int NO = NO128 * 128;
    const int n0 = mblk * 64;
    const int og0 = oblk * 128 + o;
    const int og1 = og0 + 64;

    float acc0[16], acc1[16];
#pragma unroll
    for (int i = 0; i < 16; ++i) { acc0[i] = 0.f; acc1[i] = 0.f; }

    for (int ct = 0; ct < CIN / 32; ++ct) {
        for (int r = 0; r < 2; ++r) {
            const int e = tid + 256 * r;
            const int n = e & 63, c4 = e >> 6;
            const float4 hv = *(const float4*)(H + (size_t)(n0 + n) * HC + off_in + ct * 32 + c4 * 4);
            hl[c4*4+0][n] = hv.x; hl[c4*4+1][n] = hv.y; hl[c4*4+2][n] = hv.z; hl[c4*4+3][n] = hv.w;
        }
        for (int r = 0; r < 16; ++r) {
            const int e = tid + 256 * r;
            const int c_ = e & 31, o_ = e >> 5;
            wl[c_][o_] = wfetch1(W, oblk * 128 + o_, CIN, COUT, ct * 32 + c_);
        }
        __syncthreads();
        for (int c = 0; c < 32; ++c) {
            const float wva = wl[c][o];
            const float wvb = wl[c][o + 64];
            const float* hr = &hl[c][grp * 16];
#pragma unroll
            for (int nn = 0; nn < 4; ++nn) {
                const float4 hv = *(const float4*)(hr + 4 * nn);
                acc0[4*nn+0] += wva * hv.x; acc0[4*nn+1] += wva * hv.y;
                acc0[4*nn+2] += wva * hv.z; acc0[4*nn+3] += wva * hv.w;
                acc1[4*nn+0] += wvb * hv.x; acc1[4*nn+1] += wvb * hv.y;
                acc1[4*nn+2] += wvb * hv.z; acc1[4*nn+3] += wvb * hv.w;
            }
        }
        __syncthreads();
    }

#pragma unroll
    for (int i = 0; i < 16; ++i) {
        P[(size_t)(n0 + grp * 16 + i) * NO + og0] = acc0[i];
        P[(size_t)(n0 + grp * 16 + i) * NO + og1] = acc1[i];
    }
}

// epilogue: y[q,k] = P1[nb] + P2[q]; BN+lrelu+max over k
template<int COUT>
__global__ __launch_bounds__(COUT) void edge_epi_kernel(
    const float* __restrict__ P, const int* __restrict__ idx,
    const float* __restrict__ Bs, const float* __restrict__ G, const float* __restrict__ Be,
    const float* __restrict__ Bm, const float* __restrict__ Bv,
    float* __restrict__ Hout, int off_out)
{
    constexpr int NO = 2 * COUT;
    const int blk = blockIdx.x;
    const int base = (blk >> 10) << 10;
    const int o = threadIdx.x;
    const float s = G[o] / sqrtf(Bv[o] + 1e-5f);
    const float beo = Be[o];
    const float cb = P[(size_t)blk * NO + COUT + o] + Bs[o] - Bm[o];
    float mx = -INFINITY;
    for (int k = 0; k < KNB; ++k) {
        const int m = idx[(size_t)blk * KNB + k];
        const float v = P[(size_t)(base + m) * NO + o];
        float t = (v + cb) * s + beo;
        t = t > 0.f ? t : 0.2f * t;
        mx = fmaxf(mx, t);
    }
    Hout[(size_t)blk * HC + off_out + o] = mx;
}

// ---------------- layer-0 conv ----------------
template<int CIN, int COUT, bool USEX>
__global__ __launch_bounds__(COUT) void conv_kernel(
    const float* __restrict__ H, const float* __restrict__ X, const int* __restrict__ idx,
    const float* __restrict__ W, const float* __restrict__ Bs, const float* __restrict__ G,
    const float* __restrict__ Be, const float* __restrict__ Bm, const float* __restrict__ Bv,
    float* __restrict__ Hout, int off_in, int off_out)
{
    __shared__ __align__(16) float ctr[CIN];
    __shared__ __align__(16) float nb[KNB][CIN];
    __shared__ int sidx[KNB];
    const int blk = blockIdx.x;
    const int b = blk >> 10, q = blk & 1023;
    const int tid = threadIdx.x;
    const int base = b * NPTS;

    if (tid < KNB) sidx[tid] = idx[(size_t)(base + q) * KNB + tid];
    for (int c = tid; c < CIN; c += COUT)
        ctr[c] = USEX ? XV(X, b, q, c) : H[(size_t)(base + q) * HC + off_in + c];
    __syncthreads();
    for (int t = tid; t < KNB * CIN; t += COUT) {
        const int k = t / CIN, c = t - k * CIN;
        nb[k][c] = USEX ? XV(X, b, sidx[k], c) : H[(size_t)(base + sidx[k]) * HC + off_in + c];
    }
    __syncthreads();

    float acc[KNB];
    float cacc = 0.f;
#pragma unroll
    for (int k = 0; k < KNB; ++k) acc[k] = 0.f;

    const float* wr = W + (size_t)tid * 2 * CIN;
    for (int c = 0; c < CIN; ++c) {
        const float w1 = wr[c], w2 = wr[CIN + c];
        cacc += (w2 - w1) * ctr[c];
#pragma unroll
        for (int k = 0; k < KNB; ++k) acc[k] += w1 * nb[k][c];
    }

    const int o = tid;
    const float s = G[o] / sqrtf(Bv[o] + 1e-5f);
    const float beo = Be[o];
    const float cb = cacc + Bs[o] - Bm[o];
    float mx = -INFINITY;
#pragma unroll
    for (int k = 0; k < KNB; ++k) {
        float t = (acc[k] + cb) * s + beo;
        t = t > 0.f ? t : 0.2f * t;
        mx = fmaxf(mx, t);
    }
    Hout[(size_t)(base + q) * HC + off_out + o] = mx;
}

// ---------------- lc conv + pool via MFMA (split-bf16, ~fp32 accurate) ----------------
// grid: 16 b x 16 mblk(64 pts) x 16 nblk(64 ch). wave w: rows [mblk*64+w*16, +16).
// D tile: col(lane&15)=channel, row(quad*4+reg)=point.
__global__ __launch_bounds__(256) void lcpool_mfma_kernel(
    const unsigned short* __restrict__ Hb_hi, const unsigned short* __restrict__ Hb_lo,
    const unsigned short* __restrict__ Wb_hi, const unsigned short* __restrict__ Wb_lo,
    const float* __restrict__ Bs, const float* __restrict__ G, const float* __restrict__ Be,
    const float* __restrict__ Bm, const float* __restrict__ Bv,
    float* __restrict__ pmax, float* __restrict__ psum)
{
    __shared__ float redm[4][64];
    __shared__ float reds[4][64];
    const int bid = blockIdx.x;            // 4096
    const int b = bid >> 8;
    const int mblk = (bid >> 4) & 15;
    const int nblk = bid & 15;
    const int tid = threadIdx.x;
    const int w = tid >> 6, lane = tid & 63;
    const int quad = lane >> 4, l16 = lane & 15;
    const size_t arow = ((size_t)b * 1024 + mblk * 64 + w * 16 + l16) * 512;
    const int n0 = nblk * 64;

    f32x4 acc[4];
#pragma unroll
    for (int t = 0; t < 4; ++t) acc[t] = (f32x4){0.f, 0.f, 0.f, 0.f};

    for (int kk = 0; kk < 16; ++kk) {
        const int kb = kk * 32 + quad * 8;
        const short8 ah = *(const short8*)(Hb_hi + arow + kb);
        const short8 al = *(const short8*)(Hb_lo + arow + kb);
#pragma unroll
        for (int t = 0; t < 4; ++t) {
            const size_t wrow = (size_t)(n0 + 16 * t + l16) * 512 + kb;
            const short8 bh = *(const short8*)(Wb_hi + wrow);
            const short8 bl = *(const short8*)(Wb_lo + wrow);
            acc[t] = __builtin_amdgcn_mfma_f32_16x16x32_bf16(ah, bh, acc[t], 0, 0, 0);
            acc[t] = __builtin_amdgcn_mfma_f32_16x16x32_bf16(al, bh, acc[t], 0, 0, 0);
            acc[t] = __builtin_amdgcn_mfma_f32_16x16x32_bf16(ah, bl, acc[t], 0, 0, 0);
        }
    }

#pragma unroll
    for (int t = 0; t < 4; ++t) {
        const int o = n0 + 16 * t + l16;
        const float s = G[o] / sqrtf(Bv[o] + 1e-5f);
        const float beo = Be[o];
        const float mb = Bs[o] - Bm[o];
        float pm = -INFINITY, ps = 0.f;
#pragma unroll
        for (int r = 0; r < 4; ++r) {
            float tt = (acc[t][r] + mb) * s + beo;
            tt = tt > 0.f ? tt : 0.2f * tt;
            pm = fmaxf(pm, tt); ps += tt;
        }
        pm = fmaxf(pm, __shfl_xor(pm, 16, 64));
        pm = fmaxf(pm, __shfl_xor(pm, 32, 64));
        ps += __shfl_xor(ps, 16, 64);
        ps += __shfl_xor(ps, 32, 64);
        if (quad == 0) { redm[w][16 * t + l16] = pm; reds[w][16 * t + l16] = ps; }
    }
    __syncthreads();
    if (tid < 64) {
        float m0 = redm[0][tid], s0 = reds[0][tid];
        for (int i = 1; i < 4; ++i) { m0 = fmaxf(m0, redm[i][tid]); s0 += reds[i][tid]; }
        pmax[((size_t)b * 16 + mblk) * 1024 + n0 + tid] = m0;
        psum[((size_t)b * 16 + mblk) * 1024 + n0 + tid] = s0;
    }
}

// ---------------- fp32 lcpool (fallback path) ----------------
__global__ __launch_bounds__(256, 4) void lcpool_kernel(
    const float* __restrict__ H, const float* __restrict__ W, const float* __restrict__ Bs,
    const float* __restrict__ G, const float* __restrict__ Be,
    const float* __restrict__ Bm, const float* __restrict__ Bv,
    float* __restrict__ pmax, float* __restrict__ psum)
{
    __shared__ float hl[32][68];
    __shared__ float wl[32][133];
    __shared__ float redm[4][128];
    __shared__ float reds[4][128];
    const int bid = blockIdx.x;
    const int b = bid >> 7;
    const int rem = bid & 127;
    const int oblk = rem >> 4;
    const int nblk = rem & 15;
    const int tid = threadIdx.x;
    const int o = tid & 63;
    const int grp = tid >> 6;
    const int og0 = oblk * 128 + o;
    const int og1 = og0 + 64;
    const int n0 = nblk * 64;
    const size_t hbase = (size_t)b * NPTS * HC;

    float acc0[16], acc1[16];
#pragma unroll
    for (int i = 0; i < 16; ++i) { acc0[i] = 0.f; acc1[i] = 0.f; }

    for (int ct = 0; ct < 16; ++ct) {
        for (int r = 0; r < 2; ++r) {
            const int e = tid + 256 * r;
            const int n = e & 63, c4 = e >> 6;
            const float4 hv = *(const float4*)(H + hbase + (size_t)(n0 + n) * HC + ct * 32 + c4 * 4);
            hl[c4*4+0][n] = hv.x; hl[c4*4+1][n] = hv.y; hl[c4*4+2][n] = hv.z; hl[c4*4+3][n] = hv.w;
        }
        for (int r = 0; r < 16; ++r) {
            const int e = tid + 256 * r;
            const int c_ = e & 31, o_ = e >> 5;
            wl[c_][o_] = W[(size_t)(oblk * 128 + o_) * HC + ct * 32 + c_];
        }
        __syncthreads();
        for (int c = 0; c < 32; ++c) {
            const float wva = wl[c][o];
            const float wvb = wl[c][o + 64];
            const float* hr = &hl[c][grp * 16];
#pragma unroll
            for (int nn = 0; nn < 4; ++nn) {
                const float4 hv = *(const float4*)(hr + 4 * nn);
                acc0[4*nn+0] += wva * hv.x; acc0[4*nn+1] += wva * hv.y;
                acc0[4*nn+2] += wva * hv.z; acc0[4*nn+3] += wva * hv.w;
                acc1[4*nn+0] += wvb * hv.x; acc1[4*nn+1] += wvb * hv.y;
                acc1[4*nn+2] += wvb * hv.z; acc1[4*nn+3] += wvb * hv.w;
            }
        }
        __syncthreads();
    }

#pragma unroll
    for (int p = 0; p < 2; ++p) {
        const int og = p ? og1 : og0;
        const float* acc = p ? acc1 : acc0;
        const float s = G[og] / sqrtf(Bv[og] + 1e-5f);
        const float beo = Be[og];
        const float mb = Bs[og] - Bm[og];
        float pm = -INFINITY, ps = 0.f;
#pragma unroll
        for (int i = 0; i < 16; ++i) {
            float t = (acc[i] + mb) * s + beo;
            t = t > 0.f ? t : 0.2f * t;
            pm = fmaxf(pm, t); ps += t;
        }
        redm[grp][o + 64 * p] = pm; reds[grp][o + 64 * p] = ps;
    }
    __syncthreads();
    if (grp == 0) {
#pragma unroll
        for (int p = 0; p < 2; ++p) {
            const int oo = o + 64 * p;
            float m0 = redm[0][oo], s0 = reds[0][oo];
            for (int i2 = 1; i2 < 4; ++i2) { m0 = fmaxf(m0, redm[i2][oo]); s0 += reds[i2][oo]; }
            pmax[((size_t)b * 16 + nblk) * 1024 + oblk * 128 + oo] = m0;
            psum[((size_t)b * 16 + nblk) * 1024 + oblk * 128 + oo] = s0;
        }
    }
}

__global__ void pool_reduce_kernel(const float* __restrict__ pmax, const float* __restrict__ psum,
                                   float* __restrict__ h2)
{
    const int i = blockIdx.x * 256 + threadIdx.x;
    if (i >= BB * 1024) return;
    const int b = i >> 10, o = i & 1023;
    float mx = -INFINITY, sm = 0.f;
    for (int c = 0; c < 16; ++c) {
        mx = fmaxf(mx, pmax[((size_t)b * 16 + c) * 1024 + o]);
        sm += psum[((size_t)b * 16 + c) * 1024 + o];
    }
    h2[(size_t)b * 2048 + o] = mx;
    h2[(size_t)b * 2048 + 1024 + o] = sm * (1.f / 1024.f);
}

// ---------------- FC head ----------------
__global__ void l0_kernel(const float* __restrict__ h2, const float* __restrict__ W,
                          const float* __restrict__ G, const float* __restrict__ Be,
                          const float* __restrict__ Bm, const float* __restrict__ Bv,
                          float* __restrict__ h3)
{
    const int i = blockIdx.x * 256 + threadIdx.x;
    if (i >= BB * 512) return;
    const int b = i >> 9, o = i & 511;
    const float4* w4 = (const float4*)(W + (size_t)o * 2048);
    const float4* h4p = (const float4*)(h2 + (size_t)b * 2048);
    float acc = 0.f;
    for (int c = 0; c < 512; ++c) {
        const float4 wv = w4[c]; const float4 hv = h4p[c];
        acc += wv.x*hv.x + wv.y*hv.y + wv.z*hv.z + wv.w*hv.w;
    }
    const float s = G[o] / sqrtf(Bv[o] + 1e-5f);
    float t = (acc - Bm[o]) * s + Be[o];
    t = t > 0.f ? t : 0.2f * t;
    h3[(size_t)b * 512 + o] = t;
}

__global__ void l1_kernel(const float* __restrict__ h3, const float* __restrict__ W,
                          const float* __restrict__ Bs, const float* __restrict__ G,
                          const float* __restrict__ Be, const float* __restrict__ Bm,
                          const float* __restrict__ Bv, float* __restrict__ h4o)
{
    const int i = blockIdx.x * 256 + threadIdx.x;
    if (i >= BB * 256) return;
    const int b = i >> 8, o = i & 255;
    const float4* w4 = (const float4*)(W + (size_t)o * 512);
    const float4* hv4 = (const float4*)(h3 + (size_t)b * 512);
    float acc = 0.f;
    for (int c = 0; c < 128; ++c) {
        const float4 wv = w4[c]; const float4 hv = hv4[c];
        acc += wv.x*hv.x + wv.y*hv.y + wv.z*hv.z + wv.w*hv.w;
    }
    acc += Bs[o];
    const float s = G[o] / sqrtf(Bv[o] + 1e-5f);
    float t = (acc - Bm[o]) * s + Be[o];
    t = t > 0.f ? t : 0.2f * t;
    h4o[(size_t)b * 256 + o] = t;
}

__global__ void out_kernel(const float* __restrict__ h4, const float* __restrict__ W,
                           const float* __restrict__ Bs, float* __restrict__ out)
{
    const int i = blockIdx.x * 256 + threadIdx.x;
    if (i >= BB * 40) return;
    const int b = i / 40, o = i % 40;
    const float4* w4 = (const float4*)(W + (size_t)o * 256);
    const float4* hv4 = (const float4*)(h4 + (size_t)b * 256);
    float acc = 0.f;
    for (int c = 0; c < 64; ++c) {
        const float4 wv = w4[c]; const float4 hv = hv4[c];
        acc += wv.x*hv.x + wv.y*hv.y + wv.z*hv.z + wv.w*hv.w;
    }
    acc += Bs[o];
    out[(size_t)b * 40 + o] = acc;
}

extern "C" void kernel_launch(void* const* d_in, const int* in_sizes, int n_in,
                              void* d_out, int out_size, void* d_ws, size_t ws_size,
                              hipStream_t stream)
{
    static const int expect[44] = {
        49152, 384,64,64,64,64,64, 8192,64,64,64,64,64, 16384,128,128,128,128,128,
        65536,256,256,256,256,256, 524288,1024,1024,1024,1024,1024,
        1048576,512,512,512,512, 131072,256,256,256,256,256, 10240,40};
    int bad = -1;
    if (n_in != 44) bad = 100;
    else if (out_size != BB * 40) bad = 101;
    else {
        for (int i = 0; i < 44; ++i) if (in_sizes[i] != expect[i]) { bad = i; break; }
    }
    if (bad >= 0) {
        sentinel_kernel<<<3, 256, 0, stream>>>((float*)d_out, 500.f + (float)bad);
        return;
    }

    const float* X = (const float*)d_in[0];
    const float *CW[4], *CB[4], *CG[4], *CBE[4], *CM[4], *CV[4];
    for (int i = 0; i < 4; ++i) {
        CW[i]  = (const float*)d_in[1 + 6*i]; CB[i] = (const float*)d_in[2 + 6*i];
        CG[i]  = (const float*)d_in[3 + 6*i]; CBE[i] = (const float*)d_in[4 + 6*i];
        CM[i]  = (const float*)d_in[5 + 6*i]; CV[i] = (const float*)d_in[6 + 6*i];
    }
    const float* LCW = (const float*)d_in[25]; const float* LCB = (const float*)d_in[26];
    const float* LCG = (const float*)d_in[27]; const float* LCBE = (const float*)d_in[28];
    const float* LCM = (const float*)d_in[29]; const float* LCV = (const float*)d_in[30];
    const float* L0W = (const float*)d_in[31]; const float* L0G = (const float*)d_in[32];
    const float* L0BE = (const float*)d_in[33]; const float* L0M = (const float*)d_in[34];
    const float* L0V = (const float*)d_in[35];
    const float* L1W = (const float*)d_in[36]; const float* L1B = (const float*)d_in[37];
    const float* L1G = (const float*)d_in[38]; const float* L1BE = (const float*)d_in[39];
    const float* L1M = (const float*)d_in[40]; const float* L1V = (const float*)d_in[41];
    const float* OW = (const float*)d_in[42]; const float* OB = (const float*)d_in[43];

    float* H    = (float*)d_ws;
    float* XX   = H + (size_t)BB * NPTS * HC;
    int*   IDX  = (int*)(XX + BB * NPTS);
    float* P    = (float*)(IDX + (size_t)BB * NPTS * KNB);
    float* PMAX = P + (size_t)BB * NPTS * 512;
    float* PSUM = PMAX + BB * 16 * 1024;
    float* H2   = PSUM + BB * 16 * 1024;
    float* H3   = H2 + BB * 2048;
    float* H4   = H3 + BB * 512;
    unsigned short* WBH = (unsigned short*)(H4 + BB * 256);   // 1024*512 bf16
    unsigned short* WBL = WBH + (size_t)1024 * 512;
    const size_t need_bytes = (size_t)((char*)(WBL + (size_t)1024 * 512) - (char*)H);
    const bool use_P = (ws_size >= need_bytes);

    // Hb (bf16 hi/lo) aliases P: P is dead after the last edge_epi.
    unsigned short* HBH = (unsigned short*)P;                 // 16384*512 bf16
    unsigned short* HBL = HBH + (size_t)BB * NPTS * 512;

    float* fPMAX = P;
    float* fPSUM = fPMAX + BB * 16 * 1024;
    float* fH2   = fPSUM + BB * 16 * 1024;
    float* fH3   = fH2 + BB * 2048;
    float* fH4   = fH3 + BB * 512;

    const int M = BB * NPTS;

    // ---- layer 0 ----
    xx_kernel<<<M/256, 256, 0, stream>>>(H, X, XX, 3, 0, 1);
    knn4x_kernel<<<M/4, 256, 0, stream>>>(X, XX, IDX);
    conv_kernel<3,64,true><<<M, 64, 0, stream>>>(H, X, IDX,
        CW[0], CB[0], CG[0], CBE[0], CM[0], CV[0], H, 0, 0);

    if (use_P) {
        // ---- layer 1 ----
        xx_kernel<<<M/256, 256, 0, stream>>>(H, X, XX, 64, 0, 0);
        knn8_kernel<<<M/8, 256, 0, stream>>>(H, XX, IDX, 0);
        gemm_conv_kernel<<<(M/64)*1, 256, 0, stream>>>(H, CW[1], P, 0, 64, 64, 1);
        edge_epi_kernel<64><<<M, 64, 0, stream>>>(P, IDX,
            CB[1], CG[1], CBE[1], CM[1], CV[1], H, 64);

        // ---- layer 2 ----
        xx_kernel<<<M/256, 256, 0, stream>>>(H, X, XX, 64, 64, 0);
        knn8_kernel<<<M/8, 256, 0, stream>>>(H, XX, IDX, 64);
        gemm_conv_kernel<<<(M/64)*2, 256, 0, stream>>>(H, CW[2], P, 64, 64, 128, 2);
        edge_epi_kernel<128><<<M, 128, 0, stream>>>(P, IDX,
            CB[2], CG[2], CBE[2], CM[2], CV[2], H, 128);

        // ---- layer 3 ----
        xx_kernel<<<M/256, 256, 0, stream>>>(H, X, XX, 128, 128, 0);
        knn4_kernel<128><<<M/4, 256, 0, stream>>>(H, XX, IDX, 128);
        gemm_conv_kernel<<<(M/64)*4, 256, 0, stream>>>(H, CW[3], P, 128, 128, 256, 4);
        edge_epi_kernel<256><<<M, 256, 0, stream>>>(P, IDX,
            CB[3], CG[3], CBE[3], CM[3], CV[3], H, 256);

        // ---- split-bf16 conversion (H full, LC weights) ----
        cvt_kernel<<<(M*HC/4 + 255)/256, 256, 0, stream>>>(H, HBH, HBL, M * HC / 4);
        cvt_kernel<<<(1024*512/4 + 255)/256, 256, 0, stream>>>(LCW, WBH, WBL, 1024 * 512 / 4);

        // ---- lc conv + pooling via MFMA ----
        lcpool_mfma_kernel<<<16*16*16, 256, 0, stream>>>(HBH, HBL, WBH, WBL,
            LCB, LCG, LCBE, LCM, LCV, PMAX, PSUM);
        pool_reduce_kernel<<<BB*1024/256, 256, 0, stream>>>(PMAX, PSUM, H2);
        l0_kernel<<<(BB*512+255)/256, 256, 0, stream>>>(H2, L0W, L0G, L0BE, L0M, L0V, H3);
        l1_kernel<<<(BB*256+255)/256, 256, 0, stream>>>(H3, L1W, L1B, L1G, L1BE, L1M, L1V, H4);
        out_kernel<<<(BB*40+255)/256, 256, 0, stream>>>(H4, OW, OB, (float*)d_out);
    } else {
        xx_kernel<<<M/256, 256, 0, stream>>>(H, X, XX, 64, 0, 0);
        knn8_kernel<<<M/8, 256, 0, stream>>>(H, XX, IDX, 0);
        conv_kernel<64,64,false><<<M, 64, 0, stream>>>(H, X, IDX,
            CW[1], CB[1], CG[1], CBE[1], CM[1], CV[1], H, 0, 64);

        xx_kernel<<<M/256, 256, 0, stream>>>(H, X, XX, 64, 64, 0);
        knn8_kernel<<<M/8, 256, 0, stream>>>(H, XX, IDX, 64);
        conv_kernel<64,128,false><<<M, 128, 0, stream>>>(H, X, IDX,
            CW[2], CB[2], CG[2], CBE[2], CM[2], CV[2], H, 64, 128);

        xx_kernel<<<M/256, 256, 0, stream>>>(H, X, XX, 128, 128, 0);
        knn4_kernel<128><<<M/4, 256, 0, stream>>>(H, XX, IDX, 128);
        conv_kernel<128,256,false><<<M, 256, 0, stream>>>(H, X, IDX,
            CW[3], CB[3], CG[3], CBE[3], CM[3], CV[3], H, 128, 256);

        lcpool_kernel<<<BB*8*16, 256, 0, stream>>>(H, LCW, LCB, LCG, LCBE, LCM, LCV, fPMAX, fPSUM);
        pool_reduce_kernel<<<BB*1024/256, 256, 0, stream>>>(fPMAX, fPSUM, fH2);
        l0_kernel<<<(BB*512+255)/256, 256, 0, stream>>>(fH2, L0W, L0G, L0BE, L0M, L0V, fH3);
        l1_kernel<<<(BB*256+255)/256, 256, 0, stream>>>(fH3, L1W, L1B, L1G, L1BE, L1M, L1V, fH4);
        out_kernel<<<(BB*40+255)/256, 256, 0, stream>>>(fH4, OW, OB, (float*)d_out);
    }
}

// Round 19
// 1218.047 us; speedup vs baseline: 1.0915x; 1.0915x over previous
//
#include <hip/hip_runtime.h>
#include <hip/hip_bf16.h>

#define BB 16
#define NPTS 1024
#define KNB 20
#define HC 512

typedef __attribute__((ext_vector_type(8))) short short8;
typedef __attribute__((ext_vector_type(4))) float f32x4;

__device__ __forceinline__ float XV(const float* __restrict__ X, int b, int n, int c)
{
    return X[((size_t)b * NPTS + n) * 3 + c];
}

__device__ __forceinline__ unsigned long long dist2key(float d, int m)
{
    unsigned u = __float_as_uint(d);
    u = (u & 0x80000000u) ? ~u : (u | 0x80000000u);
    return ((unsigned long long)u << 32) | (unsigned)(1023 - m);
}

__device__ __forceinline__ void wave_topk_write(unsigned long long* key,
                                                int* __restrict__ idxo,
                                                size_t obase, int lane)
{
    for (int it = 0; it < KNB; ++it) {
        unsigned long long best = 0ull; int bj = -1;
#pragma unroll
        for (int j = 0; j < 16; ++j) if (key[j] > best) { best = key[j]; bj = j; }
        unsigned long long wbest = best;
        for (int off = 32; off > 0; off >>= 1) {
            const unsigned long long o = __shfl_down(wbest, off, 64);
            if (o > wbest) wbest = o;
        }
        wbest = __shfl(wbest, 0, 64);
        if (best == wbest && bj >= 0) key[bj] = 0ull;
        if (lane == 0) idxo[obase + it] = 1023 - (int)(wbest & 0xFFFFFFFFull);
    }
}

// round-to-nearest-even fp32 -> bf16 bits
__device__ __forceinline__ unsigned short f2bf(float x)
{
    unsigned u = __float_as_uint(x);
    u += 0x7FFFu + ((u >> 16) & 1u);
    return (unsigned short)(u >> 16);
}
__device__ __forceinline__ float bf2f(unsigned short h)
{
    return __uint_as_float(((unsigned)h) << 16);
}

__global__ void sentinel_kernel(float* __restrict__ out, float val)
{
    const int i = blockIdx.x * 256 + threadIdx.x;
    if (i < BB * 40) out[i] = val;
}

// ---------------- fp32 -> (bf16 hi, bf16 lo) split conversion ----------------
__global__ void cvt_kernel(const float* __restrict__ src, unsigned short* __restrict__ hi,
                           unsigned short* __restrict__ lo, int n4)
{
    const int i = blockIdx.x * 256 + threadIdx.x;
    if (i >= n4) return;
    const float4 v = ((const float4*)src)[i];
    const float xs[4] = {v.x, v.y, v.z, v.w};
    ushort4 h, l;
    unsigned short* hp = (unsigned short*)&h;
    unsigned short* lp = (unsigned short*)&l;
#pragma unroll
    for (int j = 0; j < 4; ++j) {
        const unsigned short hb = f2bf(xs[j]);
        hp[j] = hb;
        lp[j] = f2bf(xs[j] - bf2f(hb));
    }
    ((ushort4*)hi)[i] = h;
    ((ushort4*)lo)[i] = l;
}

// ---------------- squared norms ----------------
__global__ void xx_kernel(const float* __restrict__ H, const float* __restrict__ X,
                          float* __restrict__ xx, int cin, int off_in, int use_x)
{
    const int p = blockIdx.x * blockDim.x + threadIdx.x;
    if (p >= BB * NPTS) return;
    float s = 0.f;
    if (use_x) {
        const int b = p >> 10, n = p & 1023;
        for (int c = 0; c < 3; ++c) { const float v = XV(X, b, n, c); s += v * v; }
    } else {
        const float4* r4 = (const float4*)(H + (size_t)p * HC + off_in);
        for (int c4 = 0; c4 < cin / 4; ++c4) {
            const float4 v = r4[c4];
            s += v.x*v.x + v.y*v.y + v.z*v.z + v.w*v.w;
        }
    }
    xx[p] = s;
}

// ---------------- knn, 8 queries per block (CIN=64) ----------------
__global__ __launch_bounds__(256, 3) void knn8_kernel(
    const float* __restrict__ H, const float* __restrict__ xx,
    int* __restrict__ idxo, int off_in)
{
    constexpr int CIN = 64;
    __shared__ __align__(16) float qv[8][CIN];
    __shared__ float dist[8][NPTS];
    __shared__ float sxxq[8];
    const int blk = blockIdx.x;
    const int q0g = blk * 8;
    const int b = q0g >> 10, q0 = q0g & 1023;
    const int tid = threadIdx.x;
    const int base = b * NPTS;

    for (int t = tid; t < 8 * CIN; t += 256) {
        const int q = t >> 6, c = t & 63;
        qv[q][c] = H[(size_t)(base + q0 + q) * HC + off_in + c];
    }
    if (tid < 8) sxxq[tid] = xx[base + q0 + tid];
    __syncthreads();

    const int g = tid >> 3, l = tid & 7;
    float4 aq[8][2];
#pragma unroll
    for (int q = 0; q < 8; ++q)
#pragma unroll
        for (int r = 0; r < 2; ++r)
            aq[q][r] = *(const float4*)&qv[q][4 * (l + 8 * r)];

    for (int it = 0; it < 32; ++it) {
        const int m = g + 32 * it;
        float acc[8] = {0.f,0.f,0.f,0.f,0.f,0.f,0.f,0.f};
#pragma unroll
        for (int r = 0; r < 2; ++r) {
            const float4 v = *(const float4*)(H + (size_t)(base + m) * HC + off_in + 4 * (l + 8 * r));
#pragma unroll
            for (int q = 0; q < 8; ++q)
                acc[q] += aq[q][r].x*v.x + aq[q][r].y*v.y + aq[q][r].z*v.z + aq[q][r].w*v.w;
        }
#pragma unroll
        for (int q = 0; q < 8; ++q) {
            acc[q] += __shfl_xor(acc[q], 1, 64);
            acc[q] += __shfl_xor(acc[q], 2, 64);
            acc[q] += __shfl_xor(acc[q], 4, 64);
        }
        if (l == 0) {
            const float xxm = xx[base + m];
#pragma unroll
            for (int q = 0; q < 8; ++q)
                dist[q][m] = (2.f * acc[q] - sxxq[q]) - xxm;
        }
    }
    __syncthreads();

    const int w = tid >> 6, lane = tid & 63;
    for (int qq = w; qq < 8; qq += 4) {
        unsigned long long key[16];
#pragma unroll
        for (int j = 0; j < 16; ++j) {
            const int m = lane + 64 * j;
            key[j] = dist2key(dist[qq][m], m);
        }
        wave_topk_write(key, idxo, (size_t)(base + q0 + qq) * KNB, lane);
    }
}

// ---------------- knn, 4 queries per block (CIN=128) ----------------
template<int CIN>
__global__ __launch_bounds__(256, 3) void knn4_kernel(
    const float* __restrict__ H, const float* __restrict__ xx,
    int* __restrict__ idxo, int off_in)
{
    __shared__ __align__(16) float qv[4][CIN];
    __shared__ float dist[4][NPTS];
    __shared__ float sxxq[4];
    const int blk = blockIdx.x;
    const int q0g = blk * 4;
    const int b = q0g >> 10, q0 = q0g & 1023;
    const int tid = threadIdx.x;
    const int base = b * NPTS;

    for (int t = tid; t < 4 * CIN; t += 256) {
        const int q = t / CIN, c = t - q * CIN;
        qv[q][c] = H[(size_t)(base + q0 + q) * HC + off_in + c];
    }
    if (tid < 4) sxxq[tid] = xx[base + q0 + tid];
    __syncthreads();

    const int g = tid >> 3, l = tid & 7;
    float4 aq[4][CIN / 32];
#pragma unroll
    for (int q = 0; q < 4; ++q)
#pragma unroll
        for (int r = 0; r < CIN / 32; ++r)
            aq[q][r] = *(const float4*)&qv[q][4 * (l + 8 * r)];

    for (int it = 0; it < 32; ++it) {
        const int m = g + 32 * it;
        float acc[4] = {0.f, 0.f, 0.f, 0.f};
#pragma unroll
        for (int r = 0; r < CIN / 32; ++r) {
            const float4 v = *(const float4*)(H + (size_t)(base + m) * HC + off_in + 4 * (l + 8 * r));
#pragma unroll
            for (int q = 0; q < 4; ++q)
                acc[q] += aq[q][r].x*v.x + aq[q][r].y*v.y + aq[q][r].z*v.z + aq[q][r].w*v.w;
        }
#pragma unroll
        for (int q = 0; q < 4; ++q) {
            acc[q] += __shfl_xor(acc[q], 1, 64);
            acc[q] += __shfl_xor(acc[q], 2, 64);
            acc[q] += __shfl_xor(acc[q], 4, 64);
        }
        if (l == 0) {
            const float xxm = xx[base + m];
#pragma unroll
            for (int q = 0; q < 4; ++q)
                dist[q][m] = (2.f * acc[q] - sxxq[q]) - xxm;
        }
    }
    __syncthreads();

    const int w = tid >> 6, lane = tid & 63;
    unsigned long long key[16];
#pragma unroll
    for (int j = 0; j < 16; ++j) {
        const int m = lane + 64 * j;
        key[j] = dist2key(dist[w][m], m);
    }
    wave_topk_write(key, idxo, (size_t)(base + q0 + w) * KNB, lane);
}

// knn over x (cin=3), 4 queries per block
__global__ __launch_bounds__(256, 3) void knn4x_kernel(
    const float* __restrict__ X, const float* __restrict__ xx, int* __restrict__ idxo)
{
    __shared__ float qv[4][4];
    __shared__ float dist[4][NPTS];
    __shared__ float sxxq[4];
    const int blk = blockIdx.x;
    const int q0g = blk * 4;
    const int b = q0g >> 10, q0 = q0g & 1023;
    const int tid = threadIdx.x;
    const int base = b * NPTS;

    if (tid < 4) {
        for (int c = 0; c < 3; ++c) qv[tid][c] = XV(X, b, q0 + tid, c);
        sxxq[tid] = xx[base + q0 + tid];
    }
    __syncthreads();

    for (int j = 0; j < 4; ++j) {
        const int m = tid + 256 * j;
        const float r0 = XV(X, b, m, 0), r1 = XV(X, b, m, 1), r2 = XV(X, b, m, 2);
        const float xxm = xx[base + m];
#pragma unroll
        for (int q = 0; q < 4; ++q) {
            const float acc = qv[q][0]*r0 + qv[q][1]*r1 + qv[q][2]*r2;
            dist[q][m] = (2.f * acc - sxxq[q]) - xxm;
        }
    }
    __syncthreads();

    const int w = tid >> 6, lane = tid & 63;
    unsigned long long key[16];
#pragma unroll
    for (int j = 0; j < 16; ++j) {
        const int m = lane + 64 * j;
        key[j] = dist2key(dist[w][m], m);
    }
    wave_topk_write(key, idxo, (size_t)(base + q0 + w) * KNB, lane);
}

// scalar weight fetch for gemm_conv staging: row og of [W1; W2-W1], column c
__device__ __forceinline__ float wfetch1(const float* __restrict__ W, int og,
                                         int CIN, int COUT, int c)
{
    if (og < COUT) return W[(size_t)og * 2 * CIN + c];
    const float* r0 = W + (size_t)(og - COUT) * 2 * CIN;
    return r0[CIN + c] - r0[c];
}

// ---------------- P GEMM (round-15 proven): 64 rows x 128 cols ----------------
__global__ __launch_bounds__(256, 4) void gemm_conv_kernel(
    const float* __restrict__ H, const float* __restrict__ W, float* __restrict__ P,
    int off_in, int CIN, int COUT, int NO128)
{
    __shared__ float hl[32][68];
    __shared__ float wl[32][133];
    const int mblk = blockIdx.x / NO128;
    const int oblk = blockIdx.x - mblk * NO128;
    const int tid = threadIdx.x;
    const int o = tid & 63, grp = tid >> 6;
    const int NO = NO128 * 128;
    const int n0 = mblk * 64;
    const int og0 = oblk * 128 + o;
    const int og1 = og0 + 64;

    float acc0[16], acc1[16];
#pragma unroll
    for (int i = 0; i < 16; ++i) { acc0[i] = 0.f; acc1[i] = 0.f; }

    for (int ct = 0; ct < CIN / 32; ++ct) {
        for (int r = 0; r < 2; ++r) {
            const int e = tid + 256 * r;
            const int n = e & 63, c4 = e >> 6;
            const float4 hv = *(const float4*)(H + (size_t)(n0 + n) * HC + off_in + ct * 32 + c4 * 4);
            hl[c4*4+0][n] = hv.x; hl[c4*4+1][n] = hv.y; hl[c4*4+2][n] = hv.z; hl[c4*4+3][n] = hv.w;
        }
        for (int r = 0; r < 16; ++r) {
            const int e = tid + 256 * r;
            const int c_ = e & 31, o_ = e >> 5;
            wl[c_][o_] = wfetch1(W, oblk * 128 + o_, CIN, COUT, ct * 32 + c_);
        }
        __syncthreads();
        for (int c = 0; c < 32; ++c) {
            const float wva = wl[c][o];
            const float wvb = wl[c][o + 64];
            const float* hr = &hl[c][grp * 16];
#pragma unroll
            for (int nn = 0; nn < 4; ++nn) {
                const float4 hv = *(const float4*)(hr + 4 * nn);
                acc0[4*nn+0] += wva * hv.x; acc0[4*nn+1] += wva * hv.y;
                acc0[4*nn+2] += wva * hv.z; acc0[4*nn+3] += wva * hv.w;
                acc1[4*nn+0] += wvb * hv.x; acc1[4*nn+1] += wvb * hv.y;
                acc1[4*nn+2] += wvb * hv.z; acc1[4*nn+3] += wvb * hv.w;
            }
        }
        __syncthreads();
    }

#pragma unroll
    for (int i = 0; i < 16; ++i) {
        P[(size_t)(n0 + grp * 16 + i) * NO + og0] = acc0[i];
        P[(size_t)(n0 + grp * 16 + i) * NO + og1] = acc1[i];
    }
}

// epilogue: y[q,k] = P1[nb] + P2[q]; BN+lrelu+max over k
template<int COUT>
__global__ __launch_bounds__(COUT) void edge_epi_kernel(
    const float* __restrict__ P, const int* __restrict__ idx,
    const float* __restrict__ Bs, const float* __restrict__ G, const float* __restrict__ Be,
    const float* __restrict__ Bm, const float* __restrict__ Bv,
    float* __restrict__ Hout, int off_out)
{
    constexpr int NO = 2 * COUT;
    const int blk = blockIdx.x;
    const int base = (blk >> 10) << 10;
    const int o = threadIdx.x;
    const float s = G[o] / sqrtf(Bv[o] + 1e-5f);
    const float beo = Be[o];
    const float cb = P[(size_t)blk * NO + COUT + o] + Bs[o] - Bm[o];
    float mx = -INFINITY;
    for (int k = 0; k < KNB; ++k) {
        const int m = idx[(size_t)blk * KNB + k];
        const float v = P[(size_t)(base + m) * NO + o];
        float t = (v + cb) * s + beo;
        t = t > 0.f ? t : 0.2f * t;
        mx = fmaxf(mx, t);
    }
    Hout[(size_t)blk * HC + off_out + o] = mx;
}

// ---------------- layer-0 conv ----------------
template<int CIN, int COUT, bool USEX>
__global__ __launch_bounds__(COUT) void conv_kernel(
    const float* __restrict__ H, const float* __restrict__ X, const int* __restrict__ idx,
    const float* __restrict__ W, const float* __restrict__ Bs, const float* __restrict__ G,
    const float* __restrict__ Be, const float* __restrict__ Bm, const float* __restrict__ Bv,
    float* __restrict__ Hout, int off_in, int off_out)
{
    __shared__ __align__(16) float ctr[CIN];
    __shared__ __align__(16) float nb[KNB][CIN];
    __shared__ int sidx[KNB];
    const int blk = blockIdx.x;
    const int b = blk >> 10, q = blk & 1023;
    const int tid = threadIdx.x;
    const int base = b * NPTS;

    if (tid < KNB) sidx[tid] = idx[(size_t)(base + q) * KNB + tid];
    for (int c = tid; c < CIN; c += COUT)
        ctr[c] = USEX ? XV(X, b, q, c) : H[(size_t)(base + q) * HC + off_in + c];
    __syncthreads();
    for (int t = tid; t < KNB * CIN; t += COUT) {
        const int k = t / CIN, c = t - k * CIN;
        nb[k][c] = USEX ? XV(X, b, sidx[k], c) : H[(size_t)(base + sidx[k]) * HC + off_in + c];
    }
    __syncthreads();

    float acc[KNB];
    float cacc = 0.f;
#pragma unroll
    for (int k = 0; k < KNB; ++k) acc[k] = 0.f;

    const float* wr = W + (size_t)tid * 2 * CIN;
    for (int c = 0; c < CIN; ++c) {
        const float w1 = wr[c], w2 = wr[CIN + c];
        cacc += (w2 - w1) * ctr[c];
#pragma unroll
        for (int k = 0; k < KNB; ++k) acc[k] += w1 * nb[k][c];
    }

    const int o = tid;
    const float s = G[o] / sqrtf(Bv[o] + 1e-5f);
    const float beo = Be[o];
    const float cb = cacc + Bs[o] - Bm[o];
    float mx = -INFINITY;
#pragma unroll
    for (int k = 0; k < KNB; ++k) {
        float t = (acc[k] + cb) * s + beo;
        t = t > 0.f ? t : 0.2f * t;
        mx = fmaxf(mx, t);
    }
    Hout[(size_t)(base + q) * HC + off_out + o] = mx;
}

// ---------------- lc conv + pool via MFMA v2: 128 pts x 64 ch per block ----------------
// wave w: rows mblk*128 + w*16 (+64 for second half); 2x K-unroll for pipelining.
__global__ __launch_bounds__(256) void lcpool_mfma_kernel(
    const unsigned short* __restrict__ Hb_hi, const unsigned short* __restrict__ Hb_lo,
    const unsigned short* __restrict__ Wb_hi, const unsigned short* __restrict__ Wb_lo,
    const float* __restrict__ Bs, const float* __restrict__ G, const float* __restrict__ Be,
    const float* __restrict__ Bm, const float* __restrict__ Bv,
    float* __restrict__ pmax, float* __restrict__ psum)
{
    __shared__ float redm[4][64];
    __shared__ float reds[4][64];
    const int bid = blockIdx.x;            // 16*8*16 = 2048
    const int b = bid >> 7;
    const int mblk = (bid >> 4) & 7;       // 128 pts each
    const int nblk = bid & 15;             // 64 ch each
    const int tid = threadIdx.x;
    const int w = tid >> 6, lane = tid & 63;
    const int quad = lane >> 4, l16 = lane & 15;
    const size_t arow0 = ((size_t)b * 1024 + mblk * 128 + w * 16 + l16) * 512;
    const size_t arow1 = arow0 + (size_t)64 * 512;
    const int n0 = nblk * 64;

    f32x4 acc0[4], acc1[4];
#pragma unroll
    for (int t = 0; t < 4; ++t) { acc0[t] = (f32x4){0,0,0,0}; acc1[t] = (f32x4){0,0,0,0}; }

#pragma unroll 2
    for (int kk = 0; kk < 16; ++kk) {
        const int kb = kk * 32 + quad * 8;
        const short8 ah0 = *(const short8*)(Hb_hi + arow0 + kb);
        const short8 al0 = *(const short8*)(Hb_lo + arow0 + kb);
        const short8 ah1 = *(const short8*)(Hb_hi + arow1 + kb);
        const short8 al1 = *(const short8*)(Hb_lo + arow1 + kb);
#pragma unroll
        for (int t = 0; t < 4; ++t) {
            const size_t wrow = (size_t)(n0 + 16 * t + l16) * 512 + kb;
            const short8 bh = *(const short8*)(Wb_hi + wrow);
            const short8 bl = *(const short8*)(Wb_lo + wrow);
            acc0[t] = __builtin_amdgcn_mfma_f32_16x16x32_bf16(ah0, bh, acc0[t], 0, 0, 0);
            acc0[t] = __builtin_amdgcn_mfma_f32_16x16x32_bf16(al0, bh, acc0[t], 0, 0, 0);
            acc0[t] = __builtin_amdgcn_mfma_f32_16x16x32_bf16(ah0, bl, acc0[t], 0, 0, 0);
            acc1[t] = __builtin_amdgcn_mfma_f32_16x16x32_bf16(ah1, bh, acc1[t], 0, 0, 0);
            acc1[t] = __builtin_amdgcn_mfma_f32_16x16x32_bf16(al1, bh, acc1[t], 0, 0, 0);
            acc1[t] = __builtin_amdgcn_mfma_f32_16x16x32_bf16(ah1, bl, acc1[t], 0, 0, 0);
        }
    }

#pragma unroll
    for (int t = 0; t < 4; ++t) {
        const int o = n0 + 16 * t + l16;
        const float s = G[o] / sqrtf(Bv[o] + 1e-5f);
        const float beo = Be[o];
        const float mb = Bs[o] - Bm[o];
        float pm = -INFINITY, ps = 0.f;
#pragma unroll
        for (int r = 0; r < 4; ++r) {
            float t0 = (acc0[t][r] + mb) * s + beo;
            t0 = t0 > 0.f ? t0 : 0.2f * t0;
            float t1 = (acc1[t][r] + mb) * s + beo;
            t1 = t1 > 0.f ? t1 : 0.2f * t1;
            pm = fmaxf(pm, fmaxf(t0, t1)); ps += t0 + t1;
        }
        pm = fmaxf(pm, __shfl_xor(pm, 16, 64));
        pm = fmaxf(pm, __shfl_xor(pm, 32, 64));
        ps += __shfl_xor(ps, 16, 64);
        ps += __shfl_xor(ps, 32, 64);
        if (quad == 0) { redm[w][16 * t + l16] = pm; reds[w][16 * t + l16] = ps; }
    }
    __syncthreads();
    if (tid < 64) {
        float m0 = redm[0][tid], s0 = reds[0][tid];
        for (int i = 1; i < 4; ++i) { m0 = fmaxf(m0, redm[i][tid]); s0 += reds[i][tid]; }
        pmax[((size_t)b * 8 + mblk) * 1024 + n0 + tid] = m0;
        psum[((size_t)b * 8 + mblk) * 1024 + n0 + tid] = s0;
    }
}

// ---------------- fp32 lcpool (fallback path) ----------------
__global__ __launch_bounds__(256, 4) void lcpool_kernel(
    const float* __restrict__ H, const float* __restrict__ W, const float* __restrict__ Bs,
    const float* __restrict__ G, const float* __restrict__ Be,
    const float* __restrict__ Bm, const float* __restrict__ Bv,
    float* __restrict__ pmax, float* __restrict__ psum)
{
    __shared__ float hl[32][68];
    __shared__ float wl[32][133];
    __shared__ float redm[4][128];
    __shared__ float reds[4][128];
    const int bid = blockIdx.x;
    const int b = bid >> 7;
    const int rem = bid & 127;
    const int oblk = rem >> 4;
    const int nblk = rem & 15;
    const int tid = threadIdx.x;
    const int o = tid & 63;
    const int grp = tid >> 6;
    const int og0 = oblk * 128 + o;
    const int og1 = og0 + 64;
    const int n0 = nblk * 64;
    const size_t hbase = (size_t)b * NPTS * HC;

    float acc0[16], acc1[16];
#pragma unroll
    for (int i = 0; i < 16; ++i) { acc0[i] = 0.f; acc1[i] = 0.f; }

    for (int ct = 0; ct < 16; ++ct) {
        for (int r = 0; r < 2; ++r) {
            const int e = tid + 256 * r;
            const int n = e & 63, c4 = e >> 6;
            const float4 hv = *(const float4*)(H + hbase + (size_t)(n0 + n) * HC + ct * 32 + c4 * 4);
            hl[c4*4+0][n] = hv.x; hl[c4*4+1][n] = hv.y; hl[c4*4+2][n] = hv.z; hl[c4*4+3][n] = hv.w;
        }
        for (int r = 0; r < 16; ++r) {
            const int e = tid + 256 * r;
            const int c_ = e & 31, o_ = e >> 5;
            wl[c_][o_] = W[(size_t)(oblk * 128 + o_) * HC + ct * 32 + c_];
        }
        __syncthreads();
        for (int c = 0; c < 32; ++c) {
            const float wva = wl[c][o];
            const float wvb = wl[c][o + 64];
            const float* hr = &hl[c][grp * 16];
#pragma unroll
            for (int nn = 0; nn < 4; ++nn) {
                const float4 hv = *(const float4*)(hr + 4 * nn);
                acc0[4*nn+0] += wva * hv.x; acc0[4*nn+1] += wva * hv.y;
                acc0[4*nn+2] += wva * hv.z; acc0[4*nn+3] += wva * hv.w;
                acc1[4*nn+0] += wvb * hv.x; acc1[4*nn+1] += wvb * hv.y;
                acc1[4*nn+2] += wvb * hv.z; acc1[4*nn+3] += wvb * hv.w;
            }
        }
        __syncthreads();
    }

#pragma unroll
    for (int p = 0; p < 2; ++p) {
        const int og = p ? og1 : og0;
        const float* acc = p ? acc1 : acc0;
        const float s = G[og] / sqrtf(Bv[og] + 1e-5f);
        const float beo = Be[og];
        const float mb = Bs[og] - Bm[og];
        float pm = -INFINITY, ps = 0.f;
#pragma unroll
        for (int i = 0; i < 16; ++i) {
            float t = (acc[i] + mb) * s + beo;
            t = t > 0.f ? t : 0.2f * t;
            pm = fmaxf(pm, t); ps += t;
        }
        redm[grp][o + 64 * p] = pm; reds[grp][o + 64 * p] = ps;
    }
    __syncthreads();
    if (grp == 0) {
#pragma unroll
        for (int p = 0; p < 2; ++p) {
            const int oo = o + 64 * p;
            float m0 = redm[0][oo], s0 = reds[0][oo];
            for (int i2 = 1; i2 < 4; ++i2) { m0 = fmaxf(m0, redm[i2][oo]); s0 += reds[i2][oo]; }
            pmax[((size_t)b * 16 + nblk) * 1024 + oblk * 128 + oo] = m0;
            psum[((size_t)b * 16 + nblk) * 1024 + oblk * 128 + oo] = s0;
        }
    }
}

__global__ void pool_reduce_kernel(const float* __restrict__ pmax, const float* __restrict__ psum,
                                   float* __restrict__ h2, int nch)
{
    const int i = blockIdx.x * 256 + threadIdx.x;
    if (i >= BB * 1024) return;
    const int b = i >> 10, o = i & 1023;
    float mx = -INFINITY, sm = 0.f;
    for (int c = 0; c < nch; ++c) {
        mx = fmaxf(mx, pmax[((size_t)b * nch + c) * 1024 + o]);
        sm += psum[((size_t)b * nch + c) * 1024 + o];
    }
    h2[(size_t)b * 2048 + o] = mx;
    h2[(size_t)b * 2048 + 1024 + o] = sm * (1.f / 1024.f);
}

// ---------------- FC head ----------------
__global__ void l0_kernel(const float* __restrict__ h2, const float* __restrict__ W,
                          const float* __restrict__ G, const float* __restrict__ Be,
                          const float* __restrict__ Bm, const float* __restrict__ Bv,
                          float* __restrict__ h3)
{
    const int i = blockIdx.x * 256 + threadIdx.x;
    if (i >= BB * 512) return;
    const int b = i >> 9, o = i & 511;
    const float4* w4 = (const float4*)(W + (size_t)o * 2048);
    const float4* h4p = (const float4*)(h2 + (size_t)b * 2048);
    float acc = 0.f;
    for (int c = 0; c < 512; ++c) {
        const float4 wv = w4[c]; const float4 hv = h4p[c];
        acc += wv.x*hv.x + wv.y*hv.y + wv.z*hv.z + wv.w*hv.w;
    }
    const float s = G[o] / sqrtf(Bv[o] + 1e-5f);
    float t = (acc - Bm[o]) * s + Be[o];
    t = t > 0.f ? t : 0.2f * t;
    h3[(size_t)b * 512 + o] = t;
}

__global__ void l1_kernel(const float* __restrict__ h3, const float* __restrict__ W,
                          const float* __restrict__ Bs, const float* __restrict__ G,
                          const float* __restrict__ Be, const float* __restrict__ Bm,
                          const float* __restrict__ Bv, float* __restrict__ h4o)
{
    const int i = blockIdx.x * 256 + threadIdx.x;
    if (i >= BB * 256) return;
    const int b = i >> 8, o = i & 255;
    const float4* w4 = (const float4*)(W + (size_t)o * 512);
    const float4* hv4 = (const float4*)(h3 + (size_t)b * 512);
    float acc = 0.f;
    for (int c = 0; c < 128; ++c) {
        const float4 wv = w4[c]; const float4 hv = hv4[c];
        acc += wv.x*hv.x + wv.y*hv.y + wv.z*hv.z + wv.w*hv.w;
    }
    acc += Bs[o];
    const float s = G[o] / sqrtf(Bv[o] + 1e-5f);
    float t = (acc - Bm[o]) * s + Be[o];
    t = t > 0.f ? t : 0.2f * t;
    h4o[(size_t)b * 256 + o] = t;
}

__global__ void out_kernel(const float* __restrict__ h4, const float* __restrict__ W,
                           const float* __restrict__ Bs, float* __restrict__ out)
{
    const int i = blockIdx.x * 256 + threadIdx.x;
    if (i >= BB * 40) return;
    const int b = i / 40, o = i % 40;
    const float4* w4 = (const float4*)(W + (size_t)o * 256);
    const float4* hv4 = (const float4*)(h4 + (size_t)b * 256);
    float acc = 0.f;
    for (int c = 0; c < 64; ++c) {
        const float4 wv = w4[c]; const float4 hv = hv4[c];
        acc += wv.x*hv.x + wv.y*hv.y + wv.z*hv.z + wv.w*hv.w;
    }
    acc += Bs[o];
    out[(size_t)b * 40 + o] = acc;
}

extern "C" void kernel_launch(void* const* d_in, const int* in_sizes, int n_in,
                              void* d_out, int out_size, void* d_ws, size_t ws_size,
                              hipStream_t stream)
{
    static const int expect[44] = {
        49152, 384,64,64,64,64,64, 8192,64,64,64,64,64, 16384,128,128,128,128,128,
        65536,256,256,256,256,256, 524288,1024,1024,1024,1024,1024,
        1048576,512,512,512,512, 131072,256,256,256,256,256, 10240,40};
    int bad = -1;
    if (n_in != 44) bad = 100;
    else if (out_size != BB * 40) bad = 101;
    else {
        for (int i = 0; i < 44; ++i) if (in_sizes[i] != expect[i]) { bad = i; break; }
    }
    if (bad >= 0) {
        sentinel_kernel<<<3, 256, 0, stream>>>((float*)d_out, 500.f + (float)bad);
        return;
    }

    const float* X = (const float*)d_in[0];
    const float *CW[4], *CB[4], *CG[4], *CBE[4], *CM[4], *CV[4];
    for (int i = 0; i < 4; ++i) {
        CW[i]  = (const float*)d_in[1 + 6*i]; CB[i] = (const float*)d_in[2 + 6*i];
        CG[i]  = (const float*)d_in[3 + 6*i]; CBE[i] = (const float*)d_in[4 + 6*i];
        CM[i]  = (const float*)d_in[5 + 6*i]; CV[i] = (const float*)d_in[6 + 6*i];
    }
    const float* LCW = (const float*)d_in[25]; const float* LCB = (const float*)d_in[26];
    const float* LCG = (const float*)d_in[27]; const float* LCBE = (const float*)d_in[28];
    const float* LCM = (const float*)d_in[29]; const float* LCV = (const float*)d_in[30];
    const float* L0W = (const float*)d_in[31]; const float* L0G = (const float*)d_in[32];
    const float* L0BE = (const float*)d_in[33]; const float* L0M = (const float*)d_in[34];
    const float* L0V = (const float*)d_in[35];
    const float* L1W = (const float*)d_in[36]; const float* L1B = (const float*)d_in[37];
    const float* L1G = (const float*)d_in[38]; const float* L1BE = (const float*)d_in[39];
    const float* L1M = (const float*)d_in[40]; const float* L1V = (const float*)d_in[41];
    const float* OW = (const float*)d_in[42]; const float* OB = (const float*)d_in[43];

    float* H    = (float*)d_ws;
    float* XX   = H + (size_t)BB * NPTS * HC;
    int*   IDX  = (int*)(XX + BB * NPTS);
    float* P    = (float*)(IDX + (size_t)BB * NPTS * KNB);
    float* PMAX = P + (size_t)BB * NPTS * 512;
    float* PSUM = PMAX + BB * 16 * 1024;
    float* H2   = PSUM + BB * 16 * 1024;
    float* H3   = H2 + BB * 2048;
    float* H4   = H3 + BB * 512;
    unsigned short* WBH = (unsigned short*)(H4 + BB * 256);   // 1024*512 bf16
    unsigned short* WBL = WBH + (size_t)1024 * 512;
    const size_t need_bytes = (size_t)((char*)(WBL + (size_t)1024 * 512) - (char*)H);
    const bool use_P = (ws_size >= need_bytes);

    // Hb (bf16 hi/lo) aliases P: P is dead after the last edge_epi.
    unsigned short* HBH = (unsigned short*)P;                 // 16384*512 bf16
    unsigned short* HBL = HBH + (size_t)BB * NPTS * 512;

    float* fPMAX = P;
    float* fPSUM = fPMAX + BB * 16 * 1024;
    float* fH2   = fPSUM + BB * 16 * 1024;
    float* fH3   = fH2 + BB * 2048;
    float* fH4   = fH3 + BB * 512;

    const int M = BB * NPTS;

    // ---- layer 0 ----
    xx_kernel<<<M/256, 256, 0, stream>>>(H, X, XX, 3, 0, 1);
    knn4x_kernel<<<M/4, 256, 0, stream>>>(X, XX, IDX);
    conv_kernel<3,64,true><<<M, 64, 0, stream>>>(H, X, IDX,
        CW[0], CB[0], CG[0], CBE[0], CM[0], CV[0], H, 0, 0);

    if (use_P) {
        // ---- layer 1 ----
        xx_kernel<<<M/256, 256, 0, stream>>>(H, X, XX, 64, 0, 0);
        knn8_kernel<<<M/8, 256, 0, stream>>>(H, XX, IDX, 0);
        gemm_conv_kernel<<<(M/64)*1, 256, 0, stream>>>(H, CW[1], P, 0, 64, 64, 1);
        edge_epi_kernel<64><<<M, 64, 0, stream>>>(P, IDX,
            CB[1], CG[1], CBE[1], CM[1], CV[1], H, 64);

        // ---- layer 2 ----
        xx_kernel<<<M/256, 256, 0, stream>>>(H, X, XX, 64, 64, 0);
        knn8_kernel<<<M/8, 256, 0, stream>>>(H, XX, IDX, 64);
        gemm_conv_kernel<<<(M/64)*2, 256, 0, stream>>>(H, CW[2], P, 64, 64, 128, 2);
        edge_epi_kernel<128><<<M, 128, 0, stream>>>(P, IDX,
            CB[2], CG[2], CBE[2], CM[2], CV[2], H, 128);

        // ---- layer 3 ----
        xx_kernel<<<M/256, 256, 0, stream>>>(H, X, XX, 128, 128, 0);
        knn4_kernel<128><<<M/4, 256, 0, stream>>>(H, XX, IDX, 128);
        gemm_conv_kernel<<<(M/64)*4, 256, 0, stream>>>(H, CW[3], P, 128, 128, 256, 4);
        edge_epi_kernel<256><<<M, 256, 0, stream>>>(P, IDX,
            CB[3], CG[3], CBE[3], CM[3], CV[3], H, 256);

        // ---- split-bf16 conversion (H full, LC weights) ----
        cvt_kernel<<<(M*HC/4 + 255)/256, 256, 0, stream>>>(H, HBH, HBL, M * HC / 4);
        cvt_kernel<<<(1024*512/4 + 255)/256, 256, 0, stream>>>(LCW, WBH, WBL, 1024 * 512 / 4);

        // ---- lc conv + pooling via MFMA v2 ----
        lcpool_mfma_kernel<<<16*8*16, 256, 0, stream>>>(HBH, HBL, WBH, WBL,
            LCB, LCG, LCBE, LCM, LCV, PMAX, PSUM);
        pool_reduce_kernel<<<BB*1024/256, 256, 0, stream>>>(PMAX, PSUM, H2, 8);
        l0_kernel<<<(BB*512+255)/256, 256, 0, stream>>>(H2, L0W, L0G, L0BE, L0M, L0V, H3);
        l1_kernel<<<(BB*256+255)/256, 256, 0, stream>>>(H3, L1W, L1B, L1G, L1BE, L1M, L1V, H4);
        out_kernel<<<(BB*40+255)/256, 256, 0, stream>>>(H4, OW, OB, (float*)d_out);
    } else {
        xx_kernel<<<M/256, 256, 0, stream>>>(H, X, XX, 64, 0, 0);
        knn8_kernel<<<M/8, 256, 0, stream>>>(H, XX, IDX, 0);
        conv_kernel<64,64,false><<<M, 64, 0, stream>>>(H, X, IDX,
            CW[1], CB[1], CG[1], CBE[1], CM[1], CV[1], H, 0, 64);

        xx_kernel<<<M/256, 256, 0, stream>>>(H, X, XX, 64, 64, 0);
        knn8_kernel<<<M/8, 256, 0, stream>>>(H, XX, IDX, 64);
        conv_kernel<64,128,false><<<M, 128, 0, stream>>>(H, X, IDX,
            CW[2], CB[2], CG[2], CBE[2], CM[2], CV[2], H, 64, 128);

        xx_kernel<<<M/256, 256, 0, stream>>>(H, X, XX, 128, 128, 0);
        knn4_kernel<128><<<M/4, 256, 0, stream>>>(H, XX, IDX, 128);
        conv_kernel<128,256,false><<<M, 256, 0, stream>>>(H, X, IDX,
            CW[3], CB[3], CG[3], CBE[3], CM[3], CV[3], H, 128, 256);

        lcpool_kernel<<<BB*8*16, 256, 0, stream>>>(H, LCW, LCB, LCG, LCBE, LCM, LCV, fPMAX, fPSUM);
        pool_reduce_kernel<<<BB*1024/256, 256, 0, stream>>>(fPMAX, fPSUM, fH2, 16);
        l0_kernel<<<(BB*512+255)/256, 256, 0, stream>>>(fH2, L0W, L0G, L0BE, L0M, L0V, fH3);
        l1_kernel<<<(BB*256+255)/256, 256, 0, stream>>>(fH3, L1W, L1B, L1G, L1BE, L1M, L1V, fH4);
        out_kernel<<<(BB*40+255)/256, 256, 0, stream>>>(fH4, OW, OB, (float*)d_out);
    }
}